// Round 13
// baseline (285.878 us; speedup 1.0000x reference)
//
#include <hip/hip_runtime.h>

// Problem constants (from reference)
#define NN 100000
#define EE 1600000
#define DD 128   // input dim
#define HH 128   // hidden dim
#define OO 64    // output dim

#define NPART 2          // dst-range partitions within the single fill launch
#define CAP 32           // slots per node (deg>32 handled by ovf path, proven r8/r9)
#define MAX_OVF 16384    // overflow edge capacity
#define CSTRIDE 16       // cnt padding: 16 ints = 64B line per node (atomic line-parallelism)

typedef unsigned short u16;
typedef __attribute__((ext_vector_type(8))) short bf16x8;  // 8 bf16 = 4 VGPR
typedef __attribute__((ext_vector_type(4))) float f32x4;

// ---------------------------------------------------------------------------
// bf16 helpers (RNE round, finite values only)
__device__ __forceinline__ u16 f2b(float f) {
  union { float f; unsigned u; } v; v.f = f;
  unsigned r = v.u + 0x7fffu + ((v.u >> 16) & 1u);
  return (u16)(r >> 16);
}
__device__ __forceinline__ float b2f(unsigned h) {
  union { unsigned u; float f; } v; v.u = h << 16;
  return v.f;
}
__device__ __forceinline__ void fma8(float* acc, uint4 v, float w) {
  acc[0] = fmaf(b2f(v.x & 0xffffu), w, acc[0]);
  acc[1] = fmaf(b2f(v.x >> 16), w, acc[1]);
  acc[2] = fmaf(b2f(v.y & 0xffffu), w, acc[2]);
  acc[3] = fmaf(b2f(v.y >> 16), w, acc[3]);
  acc[4] = fmaf(b2f(v.z & 0xffffu), w, acc[4]);
  acc[5] = fmaf(b2f(v.z >> 16), w, acc[5]);
  acc[6] = fmaf(b2f(v.w & 0xffffu), w, acc[6]);
  acc[7] = fmaf(b2f(v.w >> 16), w, acc[7]);
}

// ---------------------------------------------------------------------------
// Merged prep: x fp32->bf16 (blocks [0, XB)) + stacked transposed bf16 weights
// (blocks [XB, XB+192)). Per-branch code identical to the proven split kernels.
#define XB (NN * DD / 8 / 256)
__global__ __launch_bounds__(256) void cvt_k(
    const float* __restrict__ x, u16* __restrict__ xb,
    const float* __restrict__ Wr1, const float* __restrict__ Wo1,
    const float* __restrict__ Wr2, const float* __restrict__ Wo2,
    u16* __restrict__ Wt1, u16* __restrict__ Wt2) {
  if (blockIdx.x < XB) {
    int i = blockIdx.x * 256 + threadIdx.x;
    const float4* p = reinterpret_cast<const float4*>(x) + (size_t)i * 2;
    float4 a = p[0], b = p[1];
    uint4 o;
    o.x = (unsigned)f2b(a.x) | ((unsigned)f2b(a.y) << 16);
    o.y = (unsigned)f2b(a.z) | ((unsigned)f2b(a.w) << 16);
    o.z = (unsigned)f2b(b.x) | ((unsigned)f2b(b.y) << 16);
    o.w = (unsigned)f2b(b.z) | ((unsigned)f2b(b.w) << 16);
    reinterpret_cast<uint4*>(xb)[i] = o;
  } else {
    int i = (blockIdx.x - XB) * 256 + threadIdx.x;
    if (i < 128 * 256) {
      int n = i >> 8, k = i & 255;
      float v = (k < 128) ? Wr1[k * 128 + n] : Wo1[(k - 128) * 128 + n];
      Wt1[i] = f2b(v);
    } else if (i < 128 * 256 + 64 * 256) {
      int j = i - 128 * 256;
      int n = j >> 8, k = j & 255;
      float v = (k < 128) ? Wr2[k * 64 + n] : Wo2[(k - 128) * 64 + n];
      Wt2[j] = f2b(v);
    }
  }
}

// ---------------------------------------------------------------------------
// Direct bucket fill, all partitions in ONE launch: partition p = blockIdx.x /
// egrid handles dst in [p*pstep, (p+1)*pstep). Partitions touch disjoint cntp
// entries and disjoint slot slices -> order-independent, correctness-invariant.
// Block dispatch order keeps approximate temporal separation for L2 locality.
// cnt padded to one node per 64B line for TCC line-parallel atomics.
__global__ __launch_bounds__(256) void fill_direct_k(
    const int* __restrict__ ei, const float* __restrict__ w,
    int* __restrict__ cntp, uint2* __restrict__ slots,
    uint4* __restrict__ ovf, int* __restrict__ ovf_cnt,
    int egrid, int pstep, int E) {
  int part = blockIdx.x / egrid;
  int e = (blockIdx.x - part * egrid) * 256 + threadIdx.x;
  if (e >= E) return;
  int dst = ei[E + e];
  int lo = part * pstep;
  int hi = min(NN, lo + pstep);
  if (dst < lo || dst >= hi) return;
  int pos = atomicAdd(&cntp[dst * CSTRIDE], 1);
  float sig = 1.0f / (1.0f + expf(-w[e]));
  unsigned src = (unsigned)ei[e];
  if (pos < CAP) {
    slots[(size_t)dst * CAP + pos] = make_uint2(src, __float_as_uint(sig));
  } else {
    int o = atomicAdd(ovf_cnt, 1);
    if (o < MAX_OVF) ovf[o] = make_uint4((unsigned)dst, src, __float_as_uint(sig), 0u);
  }
}

// ---------------------------------------------------------------------------
// Aggregation as gather over bf16 features: 16 lanes per node, 8 bf16 each.
// Natural node order. Edge loop unrolled x8 for memory-level parallelism.
__global__ __launch_bounds__(256) void gather_k(
    const u16* __restrict__ feat, const int* __restrict__ cntp,
    const uint2* __restrict__ slots, u16* __restrict__ aggr) {
  int gid = blockIdx.x * 256 + threadIdx.x;
  int node = gid >> 4;
  int c = gid & 15;  // 8-elem chunk
  if (node >= NN) return;
  int count = min(cntp[node * CSTRIDE], CAP);
  const uint2* recs = slots + (size_t)node * CAP;
  float acc[8] = {0.f, 0.f, 0.f, 0.f, 0.f, 0.f, 0.f, 0.f};
  int e = 0;
  for (; e + 8 <= count; e += 8) {
    uint2 r[8];
#pragma unroll
    for (int j = 0; j < 8; ++j) r[j] = recs[e + j];
    uint4 v[8];
#pragma unroll
    for (int j = 0; j < 8; ++j)
      v[j] = *reinterpret_cast<const uint4*>(feat + (size_t)r[j].x * DD + c * 8);
#pragma unroll
    for (int j = 0; j < 8; ++j) fma8(acc, v[j], __uint_as_float(r[j].y));
  }
  if (e + 4 <= count) {
    uint2 r[4];
#pragma unroll
    for (int j = 0; j < 4; ++j) r[j] = recs[e + j];
    uint4 v[4];
#pragma unroll
    for (int j = 0; j < 4; ++j)
      v[j] = *reinterpret_cast<const uint4*>(feat + (size_t)r[j].x * DD + c * 8);
#pragma unroll
    for (int j = 0; j < 4; ++j) fma8(acc, v[j], __uint_as_float(r[j].y));
    e += 4;
  }
  for (; e < count; ++e) {
    uint2 r = recs[e];
    uint4 v = *reinterpret_cast<const uint4*>(feat + (size_t)r.x * DD + c * 8);
    fma8(acc, v, __uint_as_float(r.y));
  }
  uint4 o;
  o.x = (unsigned)f2b(acc[0]) | ((unsigned)f2b(acc[1]) << 16);
  o.y = (unsigned)f2b(acc[2]) | ((unsigned)f2b(acc[3]) << 16);
  o.z = (unsigned)f2b(acc[4]) | ((unsigned)f2b(acc[5]) << 16);
  o.w = (unsigned)f2b(acc[6]) | ((unsigned)f2b(acc[7]) << 16);
  *reinterpret_cast<uint4*>(aggr + (size_t)node * DD + c * 8) = o;
}

// ---------------------------------------------------------------------------
// Apply rare overflow edges into aggr (bf16) via CAS add. No-op when empty.
__global__ __launch_bounds__(256) void ovf_fix_k(const int* __restrict__ ovf_cnt,
                                                 const uint4* __restrict__ ovf,
                                                 const u16* __restrict__ feat,
                                                 u16* __restrict__ aggr) {
  int novf = min(*ovf_cnt, MAX_OVF);
  int gid = blockIdx.x * 256 + threadIdx.x;
  int idx = gid >> 6;   // overflow edge
  int word = gid & 63;  // 2-bf16 word within 128 features
  if (idx >= novf) return;
  uint4 r = ovf[idx];
  float wgt = __uint_as_float(r.z);
  unsigned fv = *reinterpret_cast<const unsigned*>(feat + (size_t)r.y * DD + word * 2);
  float m0 = b2f(fv & 0xffffu) * wgt;
  float m1 = b2f(fv >> 16) * wgt;
  unsigned* addr = reinterpret_cast<unsigned*>(aggr + (size_t)r.x * DD + word * 2);
  unsigned old = *addr, assumed;
  do {
    assumed = old;
    float a0 = b2f(assumed & 0xffffu) + m0;
    float a1 = b2f(assumed >> 16) + m1;
    unsigned nv = (unsigned)f2b(a0) | ((unsigned)f2b(a1) << 16);
    old = atomicCAS(addr, assumed, nv);
  } while (old != assumed);
}

// ---------------------------------------------------------------------------
// MFMA dual-GEMM:  C = (relu?)( [A1 | A2] @ Bt^T + bias )
template <int HO, bool RELU, bool OUTBF16>
__global__ __launch_bounds__(256) void gemm_mfma_k(
    const u16* __restrict__ A1, const u16* __restrict__ A2,
    const u16* __restrict__ Bt, const float* __restrict__ bias,
    void* __restrict__ Cout, int n_rows) {
  constexpr int CG = HO / 16;
  __shared__ u16 As[64][40];
  __shared__ u16 Bs[HO][40];

  const int t = threadIdx.x;
  const int w = t >> 6;
  const int lane = t & 63;
  const int row0 = blockIdx.x * 64;

  f32x4 acc[CG];
#pragma unroll
  for (int cg = 0; cg < CG; ++cg) acc[cg] = (f32x4){0.f, 0.f, 0.f, 0.f};

  const int arow = w * 16 + (lane & 15);
  const int kq = (lane >> 4) * 8;

  for (int k0 = 0; k0 < 256; k0 += 32) {
    {
      int node = t >> 2;
      int koff = (t & 3) * 8;
      int k = k0 + koff;
      int gr = row0 + node;
      uint4 v = make_uint4(0u, 0u, 0u, 0u);
      if (gr < n_rows) {
        const u16* src = (k < 128) ? (A1 + (size_t)gr * 128 + k)
                                   : (A2 + (size_t)gr * 128 + (k - 128));
        v = *reinterpret_cast<const uint4*>(src);
      }
      *reinterpret_cast<uint4*>(&As[node][koff]) = v;
    }
#pragma unroll
    for (int i = 0; i < CG / 4; ++i) {
      int c2 = t + i * 256;
      int n = c2 >> 2;
      int koff = (c2 & 3) * 8;
      uint4 v = *reinterpret_cast<const uint4*>(Bt + (size_t)n * 256 + k0 + koff);
      *reinterpret_cast<uint4*>(&Bs[n][koff]) = v;
    }
    __syncthreads();

    bf16x8 a = *reinterpret_cast<const bf16x8*>(&As[arow][kq]);
#pragma unroll
    for (int cg = 0; cg < CG; ++cg) {
      bf16x8 b = *reinterpret_cast<const bf16x8*>(&Bs[cg * 16 + (lane & 15)][kq]);
      acc[cg] = __builtin_amdgcn_mfma_f32_16x16x32_bf16(a, b, acc[cg], 0, 0, 0);
    }
    __syncthreads();
  }

  const int rbase = w * 16 + ((lane >> 4) << 2);
#pragma unroll
  for (int cg = 0; cg < CG; ++cg) {
    int col = cg * 16 + (lane & 15);
    float bia = bias[col];
#pragma unroll
    for (int j = 0; j < 4; ++j) {
      int gr = row0 + rbase + j;
      if (gr < n_rows) {
        float v = acc[cg][j] + bia;
        if (RELU) v = fmaxf(v, 0.f);
        if (OUTBF16) ((u16*)Cout)[(size_t)gr * HO + col] = f2b(v);
        else ((float*)Cout)[(size_t)gr * HO + col] = v;
      }
    }
  }
}

// ---------------------------------------------------------------------------
extern "C" void kernel_launch(void* const* d_in, const int* in_sizes, int n_in,
                              void* d_out, int out_size, void* d_ws, size_t ws_size,
                              hipStream_t stream) {
  const float* x   = (const float*)d_in[0];
  const float* w   = (const float*)d_in[1];
  const int*   ei  = (const int*)d_in[2];   // [2, E]: row0=src, row1=dst
  const float* Wr1 = (const float*)d_in[3];
  const float* br1 = (const float*)d_in[4];
  const float* Wo1 = (const float*)d_in[5];
  const float* Wr2 = (const float*)d_in[6];
  const float* br2 = (const float*)d_in[7];
  const float* Wo2 = (const float*)d_in[8];
  float* out = (float*)d_out;

  // Workspace layout (bytes, all offsets 16B-aligned):
  char* ws = (char*)d_ws;
  int*   cntp    = (int*)(ws);                        // N*16 ints      6,400,000
  int*   ovf_cnt = (int*)(ws + 6400000);              // 1 int (+pad)       1,024
  uint4* ovf     = (uint4*)(ws + 6803072);            // 16384 x 16B      262,144
  uint2* slots   = (uint2*)(ws + 7065216);            // N*CAP*8B      25,600,000
  u16*   xb      = (u16*)(ws + 32665216);             // N*128 bf16    25,600,000
  u16*   hb      = (u16*)(ws + 58265216);             // N*128 bf16    25,600,000
  u16*   aggrb   = (u16*)(ws + 83865216);             // N*128 bf16    25,600,000
  u16*   Wt1     = (u16*)(ws + 109465216);            // 128*256 bf16      65,536
  u16*   Wt2     = (u16*)(ws + 109530752);            // 64*256 bf16       32,768
  // total ~109.6 MB

  const int egrid = (EE + 255) / 256;

  // ---- Prep: bf16 conversions (x + weights, one launch) ----
  cvt_k<<<XB + 192, 256, 0, stream>>>(x, xb, Wr1, Wo1, Wr2, Wo2, Wt1, Wt2);

  // ---- Build dst-buckets (single launch, NPART internal partitions) ----
  hipMemsetAsync(cntp, 0, 6401024, stream);  // zeroes cntp + ovf_cnt
  {
    const int pstep = (NN + NPART - 1) / NPART;
    fill_direct_k<<<NPART * egrid, 256, 0, stream>>>(
        ei, w, cntp, slots, ovf, ovf_cnt, egrid, pstep, EE);
  }

  const int ggrid = (NN * 16 + 255) / 256;
  const int mgrid = (NN + 63) / 64;
  const int ogrid = (MAX_OVF * 64) / 256;

  // ---- Layer 1 ----
  gather_k<<<ggrid, 256, 0, stream>>>(xb, cntp, slots, aggrb);
  ovf_fix_k<<<ogrid, 256, 0, stream>>>(ovf_cnt, ovf, xb, aggrb);
  gemm_mfma_k<HH, true, true><<<mgrid, 256, 0, stream>>>(aggrb, xb, Wt1, br1, hb, NN);

  // ---- Layer 2 ----
  gather_k<<<ggrid, 256, 0, stream>>>(hb, cntp, slots, aggrb);
  ovf_fix_k<<<ogrid, 256, 0, stream>>>(ovf_cnt, ovf, hb, aggrb);
  gemm_mfma_k<OO, false, false><<<mgrid, 256, 0, stream>>>(aggrb, hb, Wt2, br2, out, NN);
}

// Round 14
// 255.542 us; speedup vs baseline: 1.1187x; 1.1187x over previous
//
#include <hip/hip_runtime.h>

// Problem constants (from reference)
#define NN 100000
#define EE 1600000
#define DD 128   // input dim
#define HH 128   // hidden dim
#define OO 64    // output dim

#define NPART 8          // dst-range partitions == XCD count (L2-local writes)
#define CAP 32           // slots per node (deg>32 handled by ovf path, proven r8/r9)
#define MAX_OVF 16384    // overflow edge capacity
#define CSTRIDE 16       // cnt padding: 16 ints = 64B line per node (atomic line-parallelism)

typedef unsigned short u16;
typedef __attribute__((ext_vector_type(8))) short bf16x8;  // 8 bf16 = 4 VGPR
typedef __attribute__((ext_vector_type(4))) float f32x4;

// ---------------------------------------------------------------------------
// bf16 helpers (RNE round, finite values only)
__device__ __forceinline__ u16 f2b(float f) {
  union { float f; unsigned u; } v; v.f = f;
  unsigned r = v.u + 0x7fffu + ((v.u >> 16) & 1u);
  return (u16)(r >> 16);
}
__device__ __forceinline__ float b2f(unsigned h) {
  union { unsigned u; float f; } v; v.u = h << 16;
  return v.f;
}
__device__ __forceinline__ void fma8(float* acc, uint4 v, float w) {
  acc[0] = fmaf(b2f(v.x & 0xffffu), w, acc[0]);
  acc[1] = fmaf(b2f(v.x >> 16), w, acc[1]);
  acc[2] = fmaf(b2f(v.y & 0xffffu), w, acc[2]);
  acc[3] = fmaf(b2f(v.y >> 16), w, acc[3]);
  acc[4] = fmaf(b2f(v.z & 0xffffu), w, acc[4]);
  acc[5] = fmaf(b2f(v.z >> 16), w, acc[5]);
  acc[6] = fmaf(b2f(v.w & 0xffffu), w, acc[6]);
  acc[7] = fmaf(b2f(v.w >> 16), w, acc[7]);
}

// ---------------------------------------------------------------------------
// Merged prep: x fp32->bf16 (blocks [0, XB)) + stacked transposed bf16 weights
// (blocks [XB, XB+192)). Per-branch code identical to the proven split kernels.
#define XB (NN * DD / 8 / 256)
__global__ __launch_bounds__(256) void cvt_k(
    const float* __restrict__ x, u16* __restrict__ xb,
    const float* __restrict__ Wr1, const float* __restrict__ Wo1,
    const float* __restrict__ Wr2, const float* __restrict__ Wo2,
    u16* __restrict__ Wt1, u16* __restrict__ Wt2) {
  if (blockIdx.x < XB) {
    int i = blockIdx.x * 256 + threadIdx.x;
    const float4* p = reinterpret_cast<const float4*>(x) + (size_t)i * 2;
    float4 a = p[0], b = p[1];
    uint4 o;
    o.x = (unsigned)f2b(a.x) | ((unsigned)f2b(a.y) << 16);
    o.y = (unsigned)f2b(a.z) | ((unsigned)f2b(a.w) << 16);
    o.z = (unsigned)f2b(b.x) | ((unsigned)f2b(b.y) << 16);
    o.w = (unsigned)f2b(b.z) | ((unsigned)f2b(b.w) << 16);
    reinterpret_cast<uint4*>(xb)[i] = o;
  } else {
    int i = (blockIdx.x - XB) * 256 + threadIdx.x;
    if (i < 128 * 256) {
      int n = i >> 8, k = i & 255;
      float v = (k < 128) ? Wr1[k * 128 + n] : Wo1[(k - 128) * 128 + n];
      Wt1[i] = f2b(v);
    } else if (i < 128 * 256 + 64 * 256) {
      int j = i - 128 * 256;
      int n = j >> 8, k = j & 255;
      float v = (k < 128) ? Wr2[k * 64 + n] : Wo2[(k - 128) * 64 + n];
      Wt2[j] = f2b(v);
    }
  }
}

// ---------------------------------------------------------------------------
// Direct bucket fill, XCD-ALIGNED partitions in one launch:
//   part = blockIdx.x & 7  -> matches the round-robin workgroup->XCD mapping,
//   so each dst-slice (3.2 MB of slots) is written ONLY from one XCD. Lines
//   accumulate in that XCD's 4 MB L2 and evict full (r13 showed 101 MB write
//   amplification from cross-XCD line bouncing; this pins each line's writer).
// Perf-only heuristic: any part<->XCD mismatch affects speed, not correctness.
__global__ __launch_bounds__(256) void fill_direct_k(
    const int* __restrict__ ei, const float* __restrict__ w,
    int* __restrict__ cntp, uint2* __restrict__ slots,
    uint4* __restrict__ ovf, int* __restrict__ ovf_cnt,
    int pstep, int E) {
  int part = blockIdx.x & (NPART - 1);
  int e = (blockIdx.x >> 3) * 256 + threadIdx.x;
  if (e >= E) return;
  int dst = ei[E + e];
  int lo = part * pstep;
  int hi = min(NN, lo + pstep);
  if (dst < lo || dst >= hi) return;
  int pos = atomicAdd(&cntp[dst * CSTRIDE], 1);
  float sig = 1.0f / (1.0f + expf(-w[e]));
  unsigned src = (unsigned)ei[e];
  if (pos < CAP) {
    slots[(size_t)dst * CAP + pos] = make_uint2(src, __float_as_uint(sig));
  } else {
    int o = atomicAdd(ovf_cnt, 1);
    if (o < MAX_OVF) ovf[o] = make_uint4((unsigned)dst, src, __float_as_uint(sig), 0u);
  }
}

// ---------------------------------------------------------------------------
// Aggregation as gather over bf16 features: 16 lanes per node, 8 bf16 each.
// Natural node order. Edge loop unrolled x8 for memory-level parallelism.
__global__ __launch_bounds__(256) void gather_k(
    const u16* __restrict__ feat, const int* __restrict__ cntp,
    const uint2* __restrict__ slots, u16* __restrict__ aggr) {
  int gid = blockIdx.x * 256 + threadIdx.x;
  int node = gid >> 4;
  int c = gid & 15;  // 8-elem chunk
  if (node >= NN) return;
  int count = min(cntp[node * CSTRIDE], CAP);
  const uint2* recs = slots + (size_t)node * CAP;
  float acc[8] = {0.f, 0.f, 0.f, 0.f, 0.f, 0.f, 0.f, 0.f};
  int e = 0;
  for (; e + 8 <= count; e += 8) {
    uint2 r[8];
#pragma unroll
    for (int j = 0; j < 8; ++j) r[j] = recs[e + j];
    uint4 v[8];
#pragma unroll
    for (int j = 0; j < 8; ++j)
      v[j] = *reinterpret_cast<const uint4*>(feat + (size_t)r[j].x * DD + c * 8);
#pragma unroll
    for (int j = 0; j < 8; ++j) fma8(acc, v[j], __uint_as_float(r[j].y));
  }
  if (e + 4 <= count) {
    uint2 r[4];
#pragma unroll
    for (int j = 0; j < 4; ++j) r[j] = recs[e + j];
    uint4 v[4];
#pragma unroll
    for (int j = 0; j < 4; ++j)
      v[j] = *reinterpret_cast<const uint4*>(feat + (size_t)r[j].x * DD + c * 8);
#pragma unroll
    for (int j = 0; j < 4; ++j) fma8(acc, v[j], __uint_as_float(r[j].y));
    e += 4;
  }
  for (; e < count; ++e) {
    uint2 r = recs[e];
    uint4 v = *reinterpret_cast<const uint4*>(feat + (size_t)r.x * DD + c * 8);
    fma8(acc, v, __uint_as_float(r.y));
  }
  uint4 o;
  o.x = (unsigned)f2b(acc[0]) | ((unsigned)f2b(acc[1]) << 16);
  o.y = (unsigned)f2b(acc[2]) | ((unsigned)f2b(acc[3]) << 16);
  o.z = (unsigned)f2b(acc[4]) | ((unsigned)f2b(acc[5]) << 16);
  o.w = (unsigned)f2b(acc[6]) | ((unsigned)f2b(acc[7]) << 16);
  *reinterpret_cast<uint4*>(aggr + (size_t)node * DD + c * 8) = o;
}

// ---------------------------------------------------------------------------
// Apply rare overflow edges into aggr (bf16) via CAS add. No-op when empty.
__global__ __launch_bounds__(256) void ovf_fix_k(const int* __restrict__ ovf_cnt,
                                                 const uint4* __restrict__ ovf,
                                                 const u16* __restrict__ feat,
                                                 u16* __restrict__ aggr) {
  int novf = min(*ovf_cnt, MAX_OVF);
  int gid = blockIdx.x * 256 + threadIdx.x;
  int idx = gid >> 6;   // overflow edge
  int word = gid & 63;  // 2-bf16 word within 128 features
  if (idx >= novf) return;
  uint4 r = ovf[idx];
  float wgt = __uint_as_float(r.z);
  unsigned fv = *reinterpret_cast<const unsigned*>(feat + (size_t)r.y * DD + word * 2);
  float m0 = b2f(fv & 0xffffu) * wgt;
  float m1 = b2f(fv >> 16) * wgt;
  unsigned* addr = reinterpret_cast<unsigned*>(aggr + (size_t)r.x * DD + word * 2);
  unsigned old = *addr, assumed;
  do {
    assumed = old;
    float a0 = b2f(assumed & 0xffffu) + m0;
    float a1 = b2f(assumed >> 16) + m1;
    unsigned nv = (unsigned)f2b(a0) | ((unsigned)f2b(a1) << 16);
    old = atomicCAS(addr, assumed, nv);
  } while (old != assumed);
}

// ---------------------------------------------------------------------------
// MFMA dual-GEMM:  C = (relu?)( [A1 | A2] @ Bt^T + bias )
template <int HO, bool RELU, bool OUTBF16>
__global__ __launch_bounds__(256) void gemm_mfma_k(
    const u16* __restrict__ A1, const u16* __restrict__ A2,
    const u16* __restrict__ Bt, const float* __restrict__ bias,
    void* __restrict__ Cout, int n_rows) {
  constexpr int CG = HO / 16;
  __shared__ u16 As[64][40];
  __shared__ u16 Bs[HO][40];

  const int t = threadIdx.x;
  const int w = t >> 6;
  const int lane = t & 63;
  const int row0 = blockIdx.x * 64;

  f32x4 acc[CG];
#pragma unroll
  for (int cg = 0; cg < CG; ++cg) acc[cg] = (f32x4){0.f, 0.f, 0.f, 0.f};

  const int arow = w * 16 + (lane & 15);
  const int kq = (lane >> 4) * 8;

  for (int k0 = 0; k0 < 256; k0 += 32) {
    {
      int node = t >> 2;
      int koff = (t & 3) * 8;
      int k = k0 + koff;
      int gr = row0 + node;
      uint4 v = make_uint4(0u, 0u, 0u, 0u);
      if (gr < n_rows) {
        const u16* src = (k < 128) ? (A1 + (size_t)gr * 128 + k)
                                   : (A2 + (size_t)gr * 128 + (k - 128));
        v = *reinterpret_cast<const uint4*>(src);
      }
      *reinterpret_cast<uint4*>(&As[node][koff]) = v;
    }
#pragma unroll
    for (int i = 0; i < CG / 4; ++i) {
      int c2 = t + i * 256;
      int n = c2 >> 2;
      int koff = (c2 & 3) * 8;
      uint4 v = *reinterpret_cast<const uint4*>(Bt + (size_t)n * 256 + k0 + koff);
      *reinterpret_cast<uint4*>(&Bs[n][koff]) = v;
    }
    __syncthreads();

    bf16x8 a = *reinterpret_cast<const bf16x8*>(&As[arow][kq]);
#pragma unroll
    for (int cg = 0; cg < CG; ++cg) {
      bf16x8 b = *reinterpret_cast<const bf16x8*>(&Bs[cg * 16 + (lane & 15)][kq]);
      acc[cg] = __builtin_amdgcn_mfma_f32_16x16x32_bf16(a, b, acc[cg], 0, 0, 0);
    }
    __syncthreads();
  }

  const int rbase = w * 16 + ((lane >> 4) << 2);
#pragma unroll
  for (int cg = 0; cg < CG; ++cg) {
    int col = cg * 16 + (lane & 15);
    float bia = bias[col];
#pragma unroll
    for (int j = 0; j < 4; ++j) {
      int gr = row0 + rbase + j;
      if (gr < n_rows) {
        float v = acc[cg][j] + bia;
        if (RELU) v = fmaxf(v, 0.f);
        if (OUTBF16) ((u16*)Cout)[(size_t)gr * HO + col] = f2b(v);
        else ((float*)Cout)[(size_t)gr * HO + col] = v;
      }
    }
  }
}

// ---------------------------------------------------------------------------
extern "C" void kernel_launch(void* const* d_in, const int* in_sizes, int n_in,
                              void* d_out, int out_size, void* d_ws, size_t ws_size,
                              hipStream_t stream) {
  const float* x   = (const float*)d_in[0];
  const float* w   = (const float*)d_in[1];
  const int*   ei  = (const int*)d_in[2];   // [2, E]: row0=src, row1=dst
  const float* Wr1 = (const float*)d_in[3];
  const float* br1 = (const float*)d_in[4];
  const float* Wo1 = (const float*)d_in[5];
  const float* Wr2 = (const float*)d_in[6];
  const float* br2 = (const float*)d_in[7];
  const float* Wo2 = (const float*)d_in[8];
  float* out = (float*)d_out;

  // Workspace layout (bytes, all offsets 16B-aligned):
  char* ws = (char*)d_ws;
  int*   cntp    = (int*)(ws);                        // N*16 ints      6,400,000
  int*   ovf_cnt = (int*)(ws + 6400000);              // 1 int (+pad)       1,024
  uint4* ovf     = (uint4*)(ws + 6803072);            // 16384 x 16B      262,144
  uint2* slots   = (uint2*)(ws + 7065216);            // N*CAP*8B      25,600,000
  u16*   xb      = (u16*)(ws + 32665216);             // N*128 bf16    25,600,000
  u16*   hb      = (u16*)(ws + 58265216);             // N*128 bf16    25,600,000
  u16*   aggrb   = (u16*)(ws + 83865216);             // N*128 bf16    25,600,000
  u16*   Wt1     = (u16*)(ws + 109465216);            // 128*256 bf16      65,536
  u16*   Wt2     = (u16*)(ws + 109530752);            // 64*256 bf16       32,768
  // total ~109.6 MB

  const int egrid = (EE + 255) / 256;

  // ---- Prep: bf16 conversions (x + weights, one launch) ----
  cvt_k<<<XB + 192, 256, 0, stream>>>(x, xb, Wr1, Wo1, Wr2, Wo2, Wt1, Wt2);

  // ---- Build dst-buckets (single launch, XCD-aligned partitions) ----
  hipMemsetAsync(cntp, 0, 6401024, stream);  // zeroes cntp + ovf_cnt
  {
    const int pstep = (NN + NPART - 1) / NPART;  // 12500 nodes -> 3.2 MB slots/XCD
    fill_direct_k<<<NPART * egrid, 256, 0, stream>>>(
        ei, w, cntp, slots, ovf, ovf_cnt, pstep, EE);
  }

  const int ggrid = (NN * 16 + 255) / 256;
  const int mgrid = (NN + 63) / 64;
  const int ogrid = (MAX_OVF * 64) / 256;

  // ---- Layer 1 ----
  gather_k<<<ggrid, 256, 0, stream>>>(xb, cntp, slots, aggrb);
  ovf_fix_k<<<ogrid, 256, 0, stream>>>(ovf_cnt, ovf, xb, aggrb);
  gemm_mfma_k<HH, true, true><<<mgrid, 256, 0, stream>>>(aggrb, xb, Wt1, br1, hb, NN);

  // ---- Layer 2 ----
  gather_k<<<ggrid, 256, 0, stream>>>(hb, cntp, slots, aggrb);
  ovf_fix_k<<<ogrid, 256, 0, stream>>>(ovf_cnt, ovf, hb, aggrb);
  gemm_mfma_k<OO, false, false><<<mgrid, 256, 0, stream>>>(aggrb, hb, Wt2, br2, out, NN);
}